// Round 15
// baseline (134.433 us; speedup 1.0000x reference)
//
#include <hip/hip_runtime.h>
#include <hip/hip_bf16.h>

typedef __attribute__((ext_vector_type(8))) short bf16x8;
typedef __attribute__((ext_vector_type(4))) short bf16x4;
typedef __attribute__((ext_vector_type(4))) float f32x4;

#define NPW 4   // batches per wave

#define A3  0.33333334f
#define B4  0.25f
#define C34 0.28867513f

__device__ const int ADJ_IDX[16][4] = {
  {0,1,7,0},{1,0,2,8},{2,1,3,9},{3,2,4,10},
  {4,3,5,11},{5,4,6,12},{6,5,13,0},{7,0,8,0},
  {8,7,9,1},{9,8,10,2},{10,9,11,3},{11,10,12,4},
  {12,11,13,5},{13,12,6,0},{0,0,0,0},{0,0,0,0}
};
__device__ const float ADJ_W[16][4] = {
  {A3,C34,A3,0.f},{B4,C34,B4,B4},{B4,B4,B4,B4},{B4,B4,B4,B4},
  {B4,B4,B4,B4},{B4,B4,C34,B4},{A3,C34,A3,0.f},{A3,A3,C34,0.f},
  {B4,C34,B4,B4},{B4,B4,B4,B4},{B4,B4,B4,B4},{B4,B4,B4,B4},
  {B4,B4,C34,B4},{A3,C34,A3,0.f},{0.f,0.f,0.f,0.f},{0.f,0.f,0.f,0.f}
};

__device__ __forceinline__ unsigned short f2b(float x) {
  unsigned u = __builtin_bit_cast(unsigned, x);
  u += 0x7FFFu + ((u >> 16) & 1u);   // RNE bf16
  return (unsigned short)(u >> 16);
}
__device__ __forceinline__ unsigned pk2(float lo, float hi) {
  float2 t; t.x = lo; t.y = hi;
  __hip_bfloat162 h = __float22bfloat162_rn(t);
  unsigned u; __builtin_memcpy(&u, &h, 4);
  return u;
}
__device__ __forceinline__ bf16x4 mk4(unsigned lo, unsigned hi) {
  uint2 u; u.x = lo; u.y = hi;
  return __builtin_bit_cast(bf16x4, u);
}

#if __has_builtin(__builtin_amdgcn_mfma_f32_16x16x16_bf16)
#define MFMA16(a, b, c) __builtin_amdgcn_mfma_f32_16x16x16_bf16((a), (b), (c), 0, 0, 0)
#elif __has_builtin(__builtin_amdgcn_mfma_f32_16x16x16bf16_1k)
#define MFMA16(a, b, c) __builtin_amdgcn_mfma_f32_16x16x16bf16_1k((a), (b), (c), 0, 0, 0)
#else
__device__ __forceinline__ f32x4 mfma16_asm(bf16x4 a, bf16x4 b, f32x4 c) {
  f32x4 d;
  asm("v_mfma_f32_16x16x16_bf16 %0, %1, %2, %3\n\ts_nop 7\n\ts_nop 7"
      : "=v"(d) : "v"(a), "v"(b), "v"(c));
  return d;
}
#define MFMA16(a, b, c) mfma16_asm((a), (b), (c))
#endif

#define SBAR() __builtin_amdgcn_sched_barrier(0)

// quarter q covers A-frag words [8q, 8q+8) = source cols [64q, 64q+64)
#define LOADQ(q) do { if (pf) { const float* _p = Xn + 64 * (q);        \
  rq[0] = *(const float4*)(_p);      rq[1] = *(const float4*)(_p + 4);  \
  rq[2] = *(const float4*)(_p + 32); rq[3] = *(const float4*)(_p + 36); } } while (0)
#define CVTQ(q) do { if (pf) {                                          \
  nxt[8*(q)+0] = pk2(rq[0].x, rq[0].y); nxt[8*(q)+1] = pk2(rq[0].z, rq[0].w); \
  nxt[8*(q)+2] = pk2(rq[1].x, rq[1].y); nxt[8*(q)+3] = pk2(rq[1].z, rq[1].w); \
  nxt[8*(q)+4] = pk2(rq[2].x, rq[2].y); nxt[8*(q)+5] = pk2(rq[2].z, rq[2].w); \
  nxt[8*(q)+6] = pk2(rq[3].x, rq[3].y); nxt[8*(q)+7] = pk2(rq[3].z, rq[3].w); } } while (0)

// ---------- weight prep (unchanged layouts) ----------
__global__ __launch_bounds__(256) void prep_w(
    const float* __restrict__ W1, const float* __restrict__ W2,
    unsigned short* __restrict__ wf)
{
  const int f = blockIdx.x * 256 + threadIdx.x;   // 20 blocks -> 5120
  if (f < 4096) {
    const int lane = f & 63, kk = (f >> 6) & 7, nt = f >> 9;
    const int col = nt * 16 + (lane & 15);
    const int k0  = kk * 32 + (lane >> 4) * 8;
    unsigned short tmp[8];
    #pragma unroll
    for (int j = 0; j < 8; ++j) tmp[j] = f2b(W1[(k0 + j) * 128 + col]);
    *(uint4*)(wf + (size_t)f * 8) = *(const uint4*)tmp;
  } else if (f < 5120) {
    const int f2i = f - 4096;                     // 0..1023
    const int lane = f2i & 63, kp = (f2i >> 6) & 3, nt = f2i >> 8;
    const int col = nt * 16 + (lane & 15);
    const int k0  = kp * 32 + (lane >> 4) * 4;
    uint4 q;
    q.x = (unsigned)f2b(W2[(k0 + 0) * 64 + col]) | ((unsigned)f2b(W2[(k0 + 1) * 64 + col]) << 16);
    q.y = (unsigned)f2b(W2[(k0 + 2) * 64 + col]) | ((unsigned)f2b(W2[(k0 + 3) * 64 + col]) << 16);
    q.z = (unsigned)f2b(W2[(k0 + 16) * 64 + col]) | ((unsigned)f2b(W2[(k0 + 17) * 64 + col]) << 16);
    q.w = (unsigned)f2b(W2[(k0 + 18) * 64 + col]) | ((unsigned)f2b(W2[(k0 + 19) * 64 + col]) << 16);
    *(uint4*)(wf + 32768 + (size_t)f2i * 8) = q;
  }
}

__global__ __launch_bounds__(512, 4) void fpm_kernel(
    const float* __restrict__ X,
    const unsigned short* __restrict__ wf,
    const float* __restrict__ b1, const float* __restrict__ b2,
    float* __restrict__ out, int Btot)
{
  __shared__ __align__(16) uint4 WL1[4096];   // 64 KiB W1 frags
  __shared__ __align__(16) uint4 WL2[1024];   // 16 KiB paired W2 frags

  const int tid  = threadIdx.x;
  const int lane = tid & 63;
  const int wv   = tid >> 6;
  const int lrow = lane & 15;
  const int lgrp = lane >> 4;

  const int gw    = blockIdx.x * 8 + wv;
  const int bbase = gw * NPW;

  // ---- bf16 double-buffer; zero-init keeps rows 14/15 zero forever ----
  unsigned xA[32], xB[32];
  #pragma unroll
  for (int i = 0; i < 32; ++i) { xA[i] = 0; xB[i] = 0; }

  // ---- prologue: load batch bbase f32, cvt -> xA (raw dies here) ----
  {
    float4 raw[16];
    #pragma unroll
    for (int i = 0; i < 16; ++i) raw[i] = float4{0.f, 0.f, 0.f, 0.f};
    if (bbase < Btot && lrow < 14) {
      const float* Xp = X + (size_t)bbase * 3584 + lrow * 256 + lgrp * 8;
      #pragma unroll
      for (int kk = 0; kk < 8; ++kk) {
        raw[2 * kk]     = *(const float4*)(Xp + kk * 32);
        raw[2 * kk + 1] = *(const float4*)(Xp + kk * 32 + 4);
      }
    }
    // one-time LDS fill overlaps the load latency
    #pragma unroll
    for (int i = 0; i < 8; ++i)
      WL1[i * 512 + tid] = ((const uint4*)wf)[i * 512 + tid];
    if (tid < 256) {
      const uint4* wf2 = (const uint4*)(wf + 32768);
      #pragma unroll
      for (int i = 0; i < 4; ++i)
        WL2[i * 256 + tid] = wf2[i * 256 + tid];
    }
    #pragma unroll
    for (int i = 0; i < 16; ++i) {
      xA[2 * i]     = pk2(raw[i].x, raw[i].y);
      xA[2 * i + 1] = pk2(raw[i].z, raw[i].w);
    }
  }

  // ---- A_hat K16 B-fragment: B[k=4*lgrp+i][n=lrow]; k=14 row = 1 (bias) ----
  unsigned amx0, amx1;
  {
    float v[4];
    #pragma unroll
    for (int i = 0; i < 4; ++i) {
      const int k = lgrp * 4 + i;
      float s = 0.f;
      if (k == 14) s = 1.f;
      else if (k < 14 && lrow < 14) {
        #pragma unroll
        for (int t = 0; t < 4; ++t)
          if (ADJ_IDX[k][t] == lrow) s += ADJ_W[k][t];
      }
      v[i] = s;
    }
    amx0 = pk2(v[0], v[1]);
    amx1 = pk2(v[2], v[3]);
  }
  const bf16x4 amx = mk4(amx0, amx1);

  // packed bias words: two 16-bit biases per register
  unsigned b1p[4], b2p[2];
  #pragma unroll
  for (int i = 0; i < 4; ++i)
    b1p[i] = (unsigned)f2b(b1[(2 * i) * 16 + lrow]) |
             ((unsigned)f2b(b1[(2 * i + 1) * 16 + lrow]) << 16);
  #pragma unroll
  for (int i = 0; i < 2; ++i)
    b2p[i] = (unsigned)f2b(b2[(2 * i) * 16 + lrow]) |
             ((unsigned)f2b(b2[(2 * i + 1) * 16 + lrow]) << 16);
  const bool isg3 = (lgrp == 3);

  __syncthreads();   // the ONLY block-wide barrier

  const bf16x8* WL1v = (const bf16x8*)WL1;
  const f32x4 zacc = {0.f, 0.f, 0.f, 0.f};

  // ---- one batch: consume cur, prefetch+convert next into nxt ----
  auto body = [&](unsigned (&cur)[32], unsigned (&nxt)[32], int b, bool pf) {
    float4 rq[4];
    const float* Xn = X + (size_t)(b + 1) * 3584 + lrow * 256 + lgrp * 8;
    LOADQ(0);
    SBAR();

    // GEMM1 + mix1 in two nt-chunks of 4 (acc1 = 16 regs)
    unsigned h1p[8][2];
    #pragma unroll
    for (int half = 0; half < 2; ++half) {
      f32x4 acc1[4];
      #pragma unroll
      for (int q = 0; q < 4; ++q) acc1[q] = zacc;
      __builtin_amdgcn_s_setprio(1);
      #pragma unroll
      for (int kk = 0; kk < 8; ++kk) {
        uint4 t;
        t.x = cur[4 * kk];     t.y = cur[4 * kk + 1];
        t.z = cur[4 * kk + 2]; t.w = cur[4 * kk + 3];
        const bf16x8 a = __builtin_bit_cast(bf16x8, t);
        #pragma unroll
        for (int q = 0; q < 4; ++q)
          acc1[q] = __builtin_amdgcn_mfma_f32_16x16x32_bf16(
              a, WL1v[((half * 4 + q) * 8 + kk) * 64 + lane], acc1[q], 0, 0, 0);
      }
      __builtin_amdgcn_s_setprio(0);
      #pragma unroll
      for (int q = 0; q < 4; ++q) {
        const int mt = half * 4 + q;
        const unsigned a0 = pk2(acc1[q][0], acc1[q][1]);
        const unsigned bw = (mt & 1) ? (b1p[mt >> 1] >> 16) : (b1p[mt >> 1] & 0xFFFFu);
        const unsigned a1 = isg3 ? bw : pk2(acc1[q][2], acc1[q][3]);
        const f32x4 h = MFMA16(mk4(a0, a1), amx, zacc);
        h1p[mt][0] = pk2(fmaxf(h[0], 0.f), fmaxf(h[1], 0.f));
        h1p[mt][1] = pk2(fmaxf(h[2], 0.f), fmaxf(h[3], 0.f));
      }
      SBAR();
      if (half == 0) { CVTQ(0); LOADQ(1); }
      else           { CVTQ(1); LOADQ(2); }
      SBAR();
    }

    // GEMM2: C2 = H1 * W2 (M16 x N64 x K128, 8 x K16)
    f32x4 acc2[4];
    #pragma unroll
    for (int nt = 0; nt < 4; ++nt) acc2[nt] = zacc;
    __builtin_amdgcn_s_setprio(1);
    #pragma unroll
    for (int kp = 0; kp < 4; ++kp) {
      const bf16x4 aE = mk4(h1p[2 * kp][0],     h1p[2 * kp][1]);
      const bf16x4 aO = mk4(h1p[2 * kp + 1][0], h1p[2 * kp + 1][1]);
      #pragma unroll
      for (int nt = 0; nt < 4; ++nt) {
        const uint4 w = WL2[(nt * 4 + kp) * 64 + lane];
        acc2[nt] = MFMA16(aE, mk4(w.x, w.y), acc2[nt]);
        acc2[nt] = MFMA16(aO, mk4(w.z, w.w), acc2[nt]);
      }
    }
    __builtin_amdgcn_s_setprio(0);
    SBAR();
    CVTQ(2); LOADQ(3);
    SBAR();

    // mix2: out^T = C2^T * Ahat_ext (+b2 via k=14); store
    float* outB = out + (size_t)b * 896;
    #pragma unroll
    for (int nt = 0; nt < 4; ++nt) {
      const unsigned a0 = pk2(acc2[nt][0], acc2[nt][1]);
      const unsigned bw = (nt & 1) ? (b2p[nt >> 1] >> 16) : (b2p[nt >> 1] & 0xFFFFu);
      const unsigned a1 = isg3 ? bw : pk2(acc2[nt][2], acc2[nt][3]);
      const f32x4 o = MFMA16(mk4(a0, a1), amx, zacc);
      if (lrow < 14) {
        float4 st; st.x = o[0]; st.y = o[1]; st.z = o[2]; st.w = o[3];
        *(float4*)(outB + lrow * 64 + nt * 16 + lgrp * 4) = st;
      }
    }
    SBAR();
    CVTQ(3);
  };

  // 4 unrolled calls with compile-time buffer swap (no runtime indexing)
  if (bbase < Btot)
    body(xA, xB, bbase,     (NPW > 1) && (bbase + 1 < Btot) && (lrow < 14));
  if (NPW > 1 && bbase + 1 < Btot)
    body(xB, xA, bbase + 1, (NPW > 2) && (bbase + 2 < Btot) && (lrow < 14));
  if (NPW > 2 && bbase + 2 < Btot)
    body(xA, xB, bbase + 2, (NPW > 3) && (bbase + 3 < Btot) && (lrow < 14));
  if (NPW > 3 && bbase + 3 < Btot)
    body(xB, xA, bbase + 3, false);
}

extern "C" void kernel_launch(void* const* d_in, const int* in_sizes, int n_in,
                              void* d_out, int out_size, void* d_ws, size_t ws_size,
                              hipStream_t stream) {
  (void)n_in; (void)out_size; (void)ws_size;
  const float* fea = (const float*)d_in[0];
  const float* W1  = (const float*)d_in[1];
  const float* b1  = (const float*)d_in[2];
  const float* W2  = (const float*)d_in[3];
  const float* b2  = (const float*)d_in[4];
  float* out = (float*)d_out;
  const int Btot = in_sizes[0] / (14 * 256);

  unsigned short* wf = (unsigned short*)d_ws;    // needs 80 KiB of d_ws
  prep_w<<<20, 256, 0, stream>>>(W1, W2, wf);

  const int per_block = 8 * NPW;
  const int grid = (Btot + per_block - 1) / per_block;
  fpm_kernel<<<grid, 512, 0, stream>>>(fea, wf, b1, b2, out, Btot);
}

// Round 16
// 73.370 us; speedup vs baseline: 1.8323x; 1.8323x over previous
//
#include <hip/hip_runtime.h>
#include <hip/hip_bf16.h>

typedef __attribute__((ext_vector_type(8))) short bf16x8;
typedef __attribute__((ext_vector_type(4))) short bf16x4;
typedef __attribute__((ext_vector_type(4))) float f32x4;

#define A3  0.33333334f
#define B4  0.25f
#define C34 0.28867513f

__device__ const int ADJ_IDX[16][4] = {
  {0,1,7,0},{1,0,2,8},{2,1,3,9},{3,2,4,10},
  {4,3,5,11},{5,4,6,12},{6,5,13,0},{7,0,8,0},
  {8,7,9,1},{9,8,10,2},{10,9,11,3},{11,10,12,4},
  {12,11,13,5},{13,12,6,0},{0,0,0,0},{0,0,0,0}
};
__device__ const float ADJ_W[16][4] = {
  {A3,C34,A3,0.f},{B4,C34,B4,B4},{B4,B4,B4,B4},{B4,B4,B4,B4},
  {B4,B4,B4,B4},{B4,B4,C34,B4},{A3,C34,A3,0.f},{A3,A3,C34,0.f},
  {B4,C34,B4,B4},{B4,B4,B4,B4},{B4,B4,B4,B4},{B4,B4,B4,B4},
  {B4,B4,C34,B4},{A3,C34,A3,0.f},{0.f,0.f,0.f,0.f},{0.f,0.f,0.f,0.f}
};

__device__ __forceinline__ unsigned short f2b(float x) {
  unsigned u = __builtin_bit_cast(unsigned, x);
  u += 0x7FFFu + ((u >> 16) & 1u);   // RNE bf16
  return (unsigned short)(u >> 16);
}
__device__ __forceinline__ unsigned pk2(float lo, float hi) {
  float2 t; t.x = lo; t.y = hi;
  __hip_bfloat162 h = __float22bfloat162_rn(t);
  unsigned u; __builtin_memcpy(&u, &h, 4);
  return u;
}
__device__ __forceinline__ bf16x4 mk4(unsigned lo, unsigned hi) {
  uint2 u; u.x = lo; u.y = hi;
  return __builtin_bit_cast(bf16x4, u);
}

#if __has_builtin(__builtin_amdgcn_mfma_f32_16x16x16_bf16)
#define MFMA16(a, b, c) __builtin_amdgcn_mfma_f32_16x16x16_bf16((a), (b), (c), 0, 0, 0)
#elif __has_builtin(__builtin_amdgcn_mfma_f32_16x16x16bf16_1k)
#define MFMA16(a, b, c) __builtin_amdgcn_mfma_f32_16x16x16bf16_1k((a), (b), (c), 0, 0, 0)
#else
__device__ __forceinline__ f32x4 mfma16_asm(bf16x4 a, bf16x4 b, f32x4 c) {
  f32x4 d;
  asm("v_mfma_f32_16x16x16_bf16 %0, %1, %2, %3\n\ts_nop 7\n\ts_nop 7"
      : "=v"(d) : "v"(a), "v"(b), "v"(c));
  return d;
}
#define MFMA16(a, b, c) mfma16_asm((a), (b), (c))
#endif

#define SBAR() __builtin_amdgcn_sched_barrier(0)

// quarter q covers A-frag words [8q, 8q+8) = source cols [64q, 64q+64), both batches
#define LOADQP(q) do { if (pf) { const float* _pA = XnA + 64 * (q);          \
  const float* _pB = XnB + 64 * (q);                                          \
  rqA[0] = *(const float4*)(_pA);      rqA[1] = *(const float4*)(_pA + 4);   \
  rqA[2] = *(const float4*)(_pA + 32); rqA[3] = *(const float4*)(_pA + 36);  \
  rqB[0] = *(const float4*)(_pB);      rqB[1] = *(const float4*)(_pB + 4);   \
  rqB[2] = *(const float4*)(_pB + 32); rqB[3] = *(const float4*)(_pB + 36); } } while (0)
#define CVTQP(q) do { if (pf) {                                               \
  curA[8*(q)+0] = pk2(rqA[0].x, rqA[0].y); curA[8*(q)+1] = pk2(rqA[0].z, rqA[0].w); \
  curA[8*(q)+2] = pk2(rqA[1].x, rqA[1].y); curA[8*(q)+3] = pk2(rqA[1].z, rqA[1].w); \
  curA[8*(q)+4] = pk2(rqA[2].x, rqA[2].y); curA[8*(q)+5] = pk2(rqA[2].z, rqA[2].w); \
  curA[8*(q)+6] = pk2(rqA[3].x, rqA[3].y); curA[8*(q)+7] = pk2(rqA[3].z, rqA[3].w); \
  curB[8*(q)+0] = pk2(rqB[0].x, rqB[0].y); curB[8*(q)+1] = pk2(rqB[0].z, rqB[0].w); \
  curB[8*(q)+2] = pk2(rqB[1].x, rqB[1].y); curB[8*(q)+3] = pk2(rqB[1].z, rqB[1].w); \
  curB[8*(q)+4] = pk2(rqB[2].x, rqB[2].y); curB[8*(q)+5] = pk2(rqB[2].z, rqB[2].w); \
  curB[8*(q)+6] = pk2(rqB[3].x, rqB[3].y); curB[8*(q)+7] = pk2(rqB[3].z, rqB[3].w); } } while (0)

// ---------- weight prep (layouts unchanged) ----------
__global__ __launch_bounds__(256) void prep_w(
    const float* __restrict__ W1, const float* __restrict__ W2,
    unsigned short* __restrict__ wf)
{
  const int f = blockIdx.x * 256 + threadIdx.x;   // 20 blocks -> 5120
  if (f < 4096) {
    const int lane = f & 63, kk = (f >> 6) & 7, nt = f >> 9;
    const int col = nt * 16 + (lane & 15);
    const int k0  = kk * 32 + (lane >> 4) * 8;
    unsigned short tmp[8];
    #pragma unroll
    for (int j = 0; j < 8; ++j) tmp[j] = f2b(W1[(k0 + j) * 128 + col]);
    *(uint4*)(wf + (size_t)f * 8) = *(const uint4*)tmp;
  } else if (f < 5120) {
    const int f2i = f - 4096;                     // 0..1023
    const int lane = f2i & 63, kp = (f2i >> 6) & 3, nt = f2i >> 8;
    const int col = nt * 16 + (lane & 15);
    const int k0  = kp * 32 + (lane >> 4) * 4;
    uint4 q;
    q.x = (unsigned)f2b(W2[(k0 + 0) * 64 + col]) | ((unsigned)f2b(W2[(k0 + 1) * 64 + col]) << 16);
    q.y = (unsigned)f2b(W2[(k0 + 2) * 64 + col]) | ((unsigned)f2b(W2[(k0 + 3) * 64 + col]) << 16);
    q.z = (unsigned)f2b(W2[(k0 + 16) * 64 + col]) | ((unsigned)f2b(W2[(k0 + 17) * 64 + col]) << 16);
    q.w = (unsigned)f2b(W2[(k0 + 18) * 64 + col]) | ((unsigned)f2b(W2[(k0 + 19) * 64 + col]) << 16);
    *(uint4*)(wf + 32768 + (size_t)f2i * 8) = q;
  }
}

__global__ __launch_bounds__(512) void fpm_kernel(
    const float* __restrict__ X,
    const unsigned short* __restrict__ wf,
    const float* __restrict__ b1, const float* __restrict__ b2,
    float* __restrict__ out, int Btot)
{
  __shared__ __align__(16) uint4 WL1[4096];   // 64 KiB W1 frags
  __shared__ __align__(16) uint4 WL2[1024];   // 16 KiB paired W2 frags

  const int tid  = threadIdx.x;
  const int lane = tid & 63;
  const int wv   = tid >> 6;
  const int lrow = lane & 15;
  const int lgrp = lane >> 4;

  const int gw    = blockIdx.x * 8 + wv;
  const int bbase = gw * 4;                    // 2 pairs per wave
  const bool rowok = (lrow < 14);

  // ---- pair buffers (packed bf16); zero-init keeps rows 14/15 zero ----
  unsigned curA[32], curB[32];
  #pragma unroll
  for (int i = 0; i < 32; ++i) { curA[i] = 0; curB[i] = 0; }

  // ---- one-time LDS fill (overlaps prologue load latency) ----
  #pragma unroll
  for (int i = 0; i < 8; ++i)
    WL1[i * 512 + tid] = ((const uint4*)wf)[i * 512 + tid];
  if (tid < 256) {
    const uint4* wf2 = (const uint4*)(wf + 32768);
    #pragma unroll
    for (int i = 0; i < 4; ++i)
      WL2[i * 256 + tid] = wf2[i * 256 + tid];
  }

  // ---- prologue: load pair 0 (two batches), sequential to cap reg peak ----
  {
    const int bA = (bbase < Btot) ? bbase : 0;
    const int bB = (bbase + 1 < Btot) ? bbase + 1 : 0;
    if (rowok) {
      float4 raw[16];
      const float* Xp = X + (size_t)bA * 3584 + lrow * 256 + lgrp * 8;
      #pragma unroll
      for (int kk = 0; kk < 8; ++kk) {
        raw[2 * kk]     = *(const float4*)(Xp + kk * 32);
        raw[2 * kk + 1] = *(const float4*)(Xp + kk * 32 + 4);
      }
      #pragma unroll
      for (int i = 0; i < 16; ++i) {
        curA[2 * i]     = pk2(raw[i].x, raw[i].y);
        curA[2 * i + 1] = pk2(raw[i].z, raw[i].w);
      }
      const float* Xq = X + (size_t)bB * 3584 + lrow * 256 + lgrp * 8;
      #pragma unroll
      for (int kk = 0; kk < 8; ++kk) {
        raw[2 * kk]     = *(const float4*)(Xq + kk * 32);
        raw[2 * kk + 1] = *(const float4*)(Xq + kk * 32 + 4);
      }
      #pragma unroll
      for (int i = 0; i < 16; ++i) {
        curB[2 * i]     = pk2(raw[i].x, raw[i].y);
        curB[2 * i + 1] = pk2(raw[i].z, raw[i].w);
      }
    }
  }

  // ---- A_hat K16 B-fragment (k=14 row = 1 for bias injection) ----
  unsigned amx0, amx1;
  {
    float v[4];
    #pragma unroll
    for (int i = 0; i < 4; ++i) {
      const int k = lgrp * 4 + i;
      float s = 0.f;
      if (k == 14) s = 1.f;
      else if (k < 14 && rowok) {
        #pragma unroll
        for (int t = 0; t < 4; ++t)
          if (ADJ_IDX[k][t] == lrow) s += ADJ_W[k][t];
      }
      v[i] = s;
    }
    amx0 = pk2(v[0], v[1]);
    amx1 = pk2(v[2], v[3]);
  }
  const bf16x4 amx = mk4(amx0, amx1);

  unsigned b1p[4], b2p[2];
  #pragma unroll
  for (int i = 0; i < 4; ++i)
    b1p[i] = (unsigned)f2b(b1[(2 * i) * 16 + lrow]) |
             ((unsigned)f2b(b1[(2 * i + 1) * 16 + lrow]) << 16);
  #pragma unroll
  for (int i = 0; i < 2; ++i)
    b2p[i] = (unsigned)f2b(b2[(2 * i) * 16 + lrow]) |
             ((unsigned)f2b(b2[(2 * i + 1) * 16 + lrow]) << 16);
  const bool isg3 = (lgrp == 3);

  __syncthreads();   // the ONLY block-wide barrier

  const bf16x8* WL1v = (const bf16x8*)WL1;
  const f32x4 zacc = {0.f, 0.f, 0.f, 0.f};

  float4 rqA[4], rqB[4];   // transient quarter-pair staging (in flight)

  // ---- consume pair (bA, bA+1); prefetch pair (bA+2, bA+3) if pf ----
  auto body = [&](int bA, bool pf) {
    const int nA = (bA + 2 < Btot) ? bA + 2 : 0;   // clamp (store-guarded)
    const int nB = (bA + 3 < Btot) ? bA + 3 : 0;
    const float* XnA = X + (size_t)nA * 3584 + lrow * 256 + lgrp * 8;
    const float* XnB = X + (size_t)nB * 3584 + lrow * 256 + lgrp * 8;
    LOADQP(0);
    SBAR();

    // ---- GEMM1 both batches, two nt-chunks; shared B-fragment reads ----
    unsigned h1pA[8][2], h1pB[8][2];
    #pragma unroll
    for (int half = 0; half < 2; ++half) {
      f32x4 accA[4], accB[4];
      #pragma unroll
      for (int q = 0; q < 4; ++q) { accA[q] = zacc; accB[q] = zacc; }
      __builtin_amdgcn_s_setprio(1);
      #pragma unroll
      for (int kk = 0; kk < 8; ++kk) {
        uint4 tA, tB;
        tA.x = curA[4 * kk];     tA.y = curA[4 * kk + 1];
        tA.z = curA[4 * kk + 2]; tA.w = curA[4 * kk + 3];
        tB.x = curB[4 * kk];     tB.y = curB[4 * kk + 1];
        tB.z = curB[4 * kk + 2]; tB.w = curB[4 * kk + 3];
        const bf16x8 aA = __builtin_bit_cast(bf16x8, tA);
        const bf16x8 aB = __builtin_bit_cast(bf16x8, tB);
        #pragma unroll
        for (int q = 0; q < 4; ++q) {
          const bf16x8 w = WL1v[((half * 4 + q) * 8 + kk) * 64 + lane];
          accA[q] = __builtin_amdgcn_mfma_f32_16x16x32_bf16(aA, w, accA[q], 0, 0, 0);
          accB[q] = __builtin_amdgcn_mfma_f32_16x16x32_bf16(aB, w, accB[q], 0, 0, 0);
        }
      }
      __builtin_amdgcn_s_setprio(0);
      // mix1 chunk for both batches
      #pragma unroll
      for (int q = 0; q < 4; ++q) {
        const int mt = half * 4 + q;
        const unsigned bw = (mt & 1) ? (b1p[mt >> 1] >> 16) : (b1p[mt >> 1] & 0xFFFFu);
        {
          const unsigned a0 = pk2(accA[q][0], accA[q][1]);
          const unsigned a1 = isg3 ? bw : pk2(accA[q][2], accA[q][3]);
          const f32x4 h = MFMA16(mk4(a0, a1), amx, zacc);
          h1pA[mt][0] = pk2(fmaxf(h[0], 0.f), fmaxf(h[1], 0.f));
          h1pA[mt][1] = pk2(fmaxf(h[2], 0.f), fmaxf(h[3], 0.f));
        }
        {
          const unsigned a0 = pk2(accB[q][0], accB[q][1]);
          const unsigned a1 = isg3 ? bw : pk2(accB[q][2], accB[q][3]);
          const f32x4 h = MFMA16(mk4(a0, a1), amx, zacc);
          h1pB[mt][0] = pk2(fmaxf(h[0], 0.f), fmaxf(h[1], 0.f));
          h1pB[mt][1] = pk2(fmaxf(h[2], 0.f), fmaxf(h[3], 0.f));
        }
      }
      SBAR();
    }
    // cur fully consumed: refill q0, launch q1
    CVTQP(0); LOADQP(1);
    SBAR();

    // ---- GEMM2 both batches; shared W2 reads ----
    f32x4 acc2A[4], acc2B[4];
    #pragma unroll
    for (int nt = 0; nt < 4; ++nt) { acc2A[nt] = zacc; acc2B[nt] = zacc; }
    __builtin_amdgcn_s_setprio(1);
    #pragma unroll
    for (int kp = 0; kp < 4; ++kp) {
      const bf16x4 aEA = mk4(h1pA[2 * kp][0],     h1pA[2 * kp][1]);
      const bf16x4 aOA = mk4(h1pA[2 * kp + 1][0], h1pA[2 * kp + 1][1]);
      const bf16x4 aEB = mk4(h1pB[2 * kp][0],     h1pB[2 * kp][1]);
      const bf16x4 aOB = mk4(h1pB[2 * kp + 1][0], h1pB[2 * kp + 1][1]);
      #pragma unroll
      for (int nt = 0; nt < 4; ++nt) {
        const uint4 w = WL2[(nt * 4 + kp) * 64 + lane];
        acc2A[nt] = MFMA16(aEA, mk4(w.x, w.y), acc2A[nt]);
        acc2A[nt] = MFMA16(aOA, mk4(w.z, w.w), acc2A[nt]);
        acc2B[nt] = MFMA16(aEB, mk4(w.x, w.y), acc2B[nt]);
        acc2B[nt] = MFMA16(aOB, mk4(w.z, w.w), acc2B[nt]);
      }
    }
    __builtin_amdgcn_s_setprio(0);
    SBAR();
    CVTQP(1); LOADQP(2);
    SBAR();

    // ---- mix2 + stores, both batches ----
    float* outA = out + (size_t)bA * 896;
    float* outB = out + (size_t)(bA + 1) * 896;
    #pragma unroll
    for (int nt = 0; nt < 4; ++nt) {
      const unsigned bw = (nt & 1) ? (b2p[nt >> 1] >> 16) : (b2p[nt >> 1] & 0xFFFFu);
      {
        const unsigned a0 = pk2(acc2A[nt][0], acc2A[nt][1]);
        const unsigned a1 = isg3 ? bw : pk2(acc2A[nt][2], acc2A[nt][3]);
        const f32x4 o = MFMA16(mk4(a0, a1), amx, zacc);
        if (rowok && bA < Btot) {
          float4 st; st.x = o[0]; st.y = o[1]; st.z = o[2]; st.w = o[3];
          *(float4*)(outA + lrow * 64 + nt * 16 + lgrp * 4) = st;
        }
      }
      {
        const unsigned a0 = pk2(acc2B[nt][0], acc2B[nt][1]);
        const unsigned a1 = isg3 ? bw : pk2(acc2B[nt][2], acc2B[nt][3]);
        const f32x4 o = MFMA16(mk4(a0, a1), amx, zacc);
        if (rowok && bA + 1 < Btot) {
          float4 st; st.x = o[0]; st.y = o[1]; st.z = o[2]; st.w = o[3];
          *(float4*)(outB + lrow * 64 + nt * 16 + lgrp * 4) = st;
        }
      }
    }
    SBAR();
    CVTQP(2); LOADQP(3);
    SBAR();
    CVTQP(3);   // waits ~a store-phase on q3; mostly covered by other waves
  };

  if (bbase < Btot) {
    const bool pf = (bbase + 3 < Btot) && rowok;
    {
      const bool pf2 = pf;  // alias for macro capture clarity
      (void)pf2;
    }
    body(bbase, pf);
    if (bbase + 2 < Btot) body(bbase + 2, false);
  }
}

extern "C" void kernel_launch(void* const* d_in, const int* in_sizes, int n_in,
                              void* d_out, int out_size, void* d_ws, size_t ws_size,
                              hipStream_t stream) {
  (void)n_in; (void)out_size; (void)ws_size;
  const float* fea = (const float*)d_in[0];
  const float* W1  = (const float*)d_in[1];
  const float* b1  = (const float*)d_in[2];
  const float* W2  = (const float*)d_in[3];
  const float* b2  = (const float*)d_in[4];
  float* out = (float*)d_out;
  const int Btot = in_sizes[0] / (14 * 256);

  unsigned short* wf = (unsigned short*)d_ws;    // needs 80 KiB of d_ws
  prep_w<<<20, 256, 0, stream>>>(W1, W2, wf);

  const int per_block = 8 * 4;
  const int grid = (Btot + per_block - 1) / per_block;
  fpm_kernel<<<grid, 512, 0, stream>>>(fea, wf, b1, b2, out, Btot);
}